// Round 13
// baseline (169.190 us; speedup 1.0000x reference)
//
#include <hip/hip_runtime.h>
#include <stdint.h>

typedef __attribute__((ext_vector_type(8))) short short8;
typedef __attribute__((ext_vector_type(4))) short short4v;
typedef __attribute__((ext_vector_type(4))) float f32x4;
typedef __attribute__((ext_vector_type(4))) int   i32x4;

#define T_STEPS 200
#define BATCH   128
#define UNITS   256
#define N3      768
#define EMB_D   100

#define NG 128      // one block per batch row
#define GWAVES 16   // waves per gru block

#define W8_BYTES  (48 * 4 * 64 * 16)         // 196608 == 256*768 i8 frags
#define WFX_ELEMS (48 * 4 * 64 * 8)          // 98304  == 128*768 bf16 (K padded 100->128)

#define NLOG2E  -1.4426950408889634f         // -log2(e), folded into z/r columns
#define N2LOG2E -2.8853900817779268f         // -2*log2(e), folded into c columns

#if __has_builtin(__builtin_amdgcn_exp2f)
#define EXP2(x) __builtin_amdgcn_exp2f(x)
#else
#define EXP2(x) __expf((x) * 0.6931471805599453f)
#endif

__device__ __forceinline__ unsigned short f2bf(float f) {
  unsigned int u = __float_as_uint(f);
  u = (u + 0x7fffu + ((u >> 16) & 1u)) >> 16;   // RNE
  return (unsigned short)u;
}
__device__ __forceinline__ float sigmoidf_(float x) {
  return __builtin_amdgcn_rcpf(1.0f + __expf(-x));
}

// ------- kernel 0: fused per-column absmax + i8 quant; kernel->bf16 frags; bsum ------
__global__ void prep_kernel(const float* __restrict__ kern,
                            const float* __restrict__ rkern,
                            const float* __restrict__ bias_i,
                            const float* __restrict__ bias_r,
                            signed char* __restrict__ w8,
                            unsigned short* __restrict__ wfx,
                            float* __restrict__ bsum,
                            float* __restrict__ cm) {
  int b = blockIdx.x;
  int tid = threadIdx.x;
  if (b < 48) {
    __shared__ float red[256];
    __shared__ float cmv[16];
    int ntg = b;
    int col = tid & 15;
    int n = ntg * 16 + col;
    int k0 = (tid >> 4) * 16;
    float m = 0.0f;
#pragma unroll 4
    for (int k = k0; k < k0 + 16; ++k) m = fmaxf(m, fabsf(rkern[k * N3 + n]));
    red[tid] = m;
    __syncthreads();
    if (tid < 16) {
      float mm = red[tid];
#pragma unroll
      for (int s = 1; s < 16; ++s) mm = fmaxf(mm, red[tid + 16 * s]);
      mm = (mm > 0.0f) ? mm : 1.0f;
      cmv[tid] = mm;
      cm[n] = mm;                           // n == ntg*16 + tid here
    }
    __syncthreads();
    // quantize: thread tid -> bytes [ntg*4096 + tid*16, +16)
    int l = tid & 63, kc = tid >> 6;
    int nn = ntg * 16 + (l & 15);
    float inv127 = 127.0f / cmv[l & 15];
    union { signed char c[16]; i32x4 v; } pk;
#pragma unroll
    for (int e = 0; e < 16; ++e) {
      int k = kc * 64 + (e & 3) + ((l >> 4) & 3) * 4 + ((e >> 2) & 3) * 16;
      float v = rintf(rkern[k * N3 + nn] * inv127);
      v = fminf(127.0f, fmaxf(-127.0f, v));
      pk.c[e] = (signed char)(int)v;
    }
    *(i32x4*)&w8[ntg * 4096 + tid * 16] = pk.v;
  } else {
    int i = (b - 48) * 256 + tid;
    if (i < WFX_ELEMS) {
      int e = i & 7, l = (i >> 3) & 63, ks = (i >> 9) & 3, nt = i >> 11;
      int k = ks * 32 + (e >> 2) * 16 + ((l >> 4) & 3) * 4 + (e & 3);
      int n = nt * 16 + (l & 15);
      float gf = (n < 2 * UNITS) ? NLOG2E : N2LOG2E; // fold exp2 scale into columns
      wfx[i] = (k < EMB_D) ? f2bf(kern[k * N3 + n] * gf) : (unsigned short)0;
    } else if (i < WFX_ELEMS + N3) {
      int c = i - WFX_ELEMS;
      float gf = (c < 2 * UNITS) ? NLOG2E : N2LOG2E;
      bsum[c] = (bias_i[c] + ((c < 2 * UNITS) ? bias_r[c] : 0.0f)) * gf;
    }
  }
}

// -------- kernel 1: MX = emb[inputs] @ kernel' + bsum', gate-aligned, direct write ---
// MXzr[m*256+u] = z|(r<<16) bf16 pair; MXc[m*256+u] = c bf16, m = t*128 + b.
__global__ __launch_bounds__(256) void mx_kernel(
    const int* __restrict__ inputs, const float* __restrict__ emb,
    const unsigned short* __restrict__ wfx, const float* __restrict__ bsum,
    unsigned int* __restrict__ MXzr, unsigned short* __restrict__ MXc) {
  __shared__ unsigned short Af[4 * 64 * 8];   // 4 KB A-fragments (16 rows x K128)
  int tile = blockIdx.x;                      // 1600 tiles of 16 m-rows
  int tid = threadIdx.x;
  int lane = tid & 63;
  int wv = tid >> 6;                          // 0..3
  {
    short8 z = {0, 0, 0, 0, 0, 0, 0, 0};
    ((short8*)Af)[tid] = z;
  }
  __syncthreads();
  // vectorized gather: 16 rows x 25 float4 chunks (emb rows 16B-aligned at c%4==0)
  for (int i = tid; i < 512; i += 256) {
    int r = i >> 5, c4 = i & 31;
    if (c4 < 25) {
      int m = tile * 16 + r;                  // m = t*128 + b
      int ti = m >> 7, b = m & 127;
      int word = inputs[b * T_STEPS + ti];
      f32x4 v = *(const f32x4*)(emb + word * EMB_D + c4 * 4);
      int c = c4 * 4;
      int idx0 = ((c >> 5) * 64 + (r + 16 * ((c >> 2) & 3))) * 8 + ((c >> 4) & 1) * 4;
      short4v p = {(short)f2bf(v.x), (short)f2bf(v.y), (short)f2bf(v.z), (short)f2bf(v.w)};
      *(short4v*)&Af[idx0] = p;               // (c&3)=0..3 are contiguous in frag order
    }
  }
  __syncthreads();
  short8 a0 = ((short8*)Af)[0 * 64 + lane];
  short8 a1 = ((short8*)Af)[1 * 64 + lane];
  short8 a2 = ((short8*)Af)[2 * 64 + lane];
  short8 a3 = ((short8*)Af)[3 * 64 + lane];
  int r0 = (lane >> 4) * 4;
#pragma unroll
  for (int p = 0; p < 4; ++p) {
    int trp = wv * 4 + p;                     // gate triple 0..15
    int u = trp * 16 + (lane & 15);
    float bsz = bsum[u];
    float bsr = bsum[u + UNITS];
    float bsc = bsum[u + 2 * UNITS];
    f32x4 az = {0.f, 0.f, 0.f, 0.f}, ar = {0.f, 0.f, 0.f, 0.f}, ac = {0.f, 0.f, 0.f, 0.f};
    const short8* bpz = (const short8*)(wfx) + (trp * 4) * 64 + lane;
    const short8* bpr = (const short8*)(wfx) + ((16 + trp) * 4) * 64 + lane;
    const short8* bpc = (const short8*)(wfx) + ((32 + trp) * 4) * 64 + lane;
    az = __builtin_amdgcn_mfma_f32_16x16x32_bf16(a0, bpz[0],   az, 0, 0, 0);
    ar = __builtin_amdgcn_mfma_f32_16x16x32_bf16(a0, bpr[0],   ar, 0, 0, 0);
    ac = __builtin_amdgcn_mfma_f32_16x16x32_bf16(a0, bpc[0],   ac, 0, 0, 0);
    az = __builtin_amdgcn_mfma_f32_16x16x32_bf16(a1, bpz[64],  az, 0, 0, 0);
    ar = __builtin_amdgcn_mfma_f32_16x16x32_bf16(a1, bpr[64],  ar, 0, 0, 0);
    ac = __builtin_amdgcn_mfma_f32_16x16x32_bf16(a1, bpc[64],  ac, 0, 0, 0);
    az = __builtin_amdgcn_mfma_f32_16x16x32_bf16(a2, bpz[128], az, 0, 0, 0);
    ar = __builtin_amdgcn_mfma_f32_16x16x32_bf16(a2, bpr[128], ar, 0, 0, 0);
    ac = __builtin_amdgcn_mfma_f32_16x16x32_bf16(a2, bpc[128], ac, 0, 0, 0);
    az = __builtin_amdgcn_mfma_f32_16x16x32_bf16(a3, bpz[192], az, 0, 0, 0);
    ar = __builtin_amdgcn_mfma_f32_16x16x32_bf16(a3, bpr[192], ar, 0, 0, 0);
    ac = __builtin_amdgcn_mfma_f32_16x16x32_bf16(a3, bpc[192], ac, 0, 0, 0);
#pragma unroll
    for (int j = 0; j < 4; ++j) {
      size_t m = (size_t)tile * 16 + r0 + j;
      unsigned int zr = (unsigned int)f2bf(az[j] + bsz) | ((unsigned int)f2bf(ar[j] + bsr) << 16);
      MXzr[m * 256 + u] = zr;
      MXc[m * 256 + u] = f2bf(ac[j] + bsc);
    }
  }
}

// -------- kernel 2: 16 waves (4/SIMD), one gate wave per SIMD via zrc LDS ------------
__global__ __launch_bounds__(1024) void gru_kernel(
    const unsigned int* __restrict__ MXzr, const unsigned short* __restrict__ MXc,
    const signed char* __restrict__ w8,
    const float* __restrict__ cm, const float* __restrict__ bias_r,
    const float* __restrict__ w_out, const float* __restrict__ b_out,
    float* __restrict__ out) {
  __shared__ i32x4 hAv[2][4 * 64];            // 8 KB: double-buffered h i8 A-frags
  __shared__ int zrc[GWAVES * 48];            // 3 KB: row-0 accumulator dump
  __shared__ float hout[UNITS];               // 1 KB: final h for output GEMV

  int g = blockIdx.x;                          // batch row 0..127
  int tid = threadIdx.x;
  int lane = tid & 63;
  int w = tid >> 6;                            // 0..15

  // MFMA side: wave w owns gate-aligned ntile triple {w, 16+w, 32+w} (round-11 layout)
  i32x4 bz[4], br[4], bc[4];
  {
    const i32x4* wsrc = (const i32x4*)w8 + lane;
#pragma unroll
    for (int kc = 0; kc < 4; ++kc) {
      bz[kc] = wsrc[(size_t)((w)*4 + kc) * 64];
      br[kc] = wsrc[(size_t)((16 + w) * 4 + kc) * 64];
      bc[kc] = wsrc[(size_t)((32 + w) * 4 + kc) * 64];
    }
  }
  if (tid < 512) { i32x4 z = {0, 0, 0, 0}; ((i32x4*)hAv)[tid] = z; }

  // gate side: waves {0,5,10,15} (one per SIMD under both w%4 and w>>2 mappings),
  // gate wave gw handles units u = gw*64 + lane with ALL 64 lanes useful.
  bool is_gate = (w % 5) == 0;
  int gw = w / 5;                              // 0..3 for w in {0,5,10,15}
  int u = gw * 64 + lane;

  float szp = 0.f, srp = 0.f, scp = 0.f, brcp = 0.f;
  if (is_gate) {
    const float inv = 1.0f / (127.0f * 127.0f);
    szp = cm[u] * inv * NLOG2E;
    srp = cm[u + UNITS] * inv * NLOG2E;
    scp = cm[u + 2 * UNITS] * inv * N2LOG2E;
    brcp = bias_r[2 * UNITS + u] * N2LOG2E;
  }

  // zrc read base for unit u: source wave u>>4, col u&15
  int zaddr = (u >> 4) * 48 + (u & 15);
  // hA byte-write base for (row0, u): plane kc=u>>6, lane la=16*((u>>2)&3),
  // byte e=(u&3)+4*((u>>4)&3). Buffer stride 4096 B. Bijective over u.
  int hwb = (u >> 6) * 1024 + (16 * ((u >> 2) & 3)) * 16 + (u & 3) + 4 * ((u >> 4) & 3);

  float h = 0.0f;
  const unsigned int* mzr = MXzr + (size_t)g * 256 + u;
  const unsigned short* mc = MXc + (size_t)g * 256 + u;
  const size_t mxstride = (size_t)BATCH * 256;
  const float MAGIC = 12582912.0f;             // 2^23 + 2^22

  // prefetch t=0 (gate waves only; wave-uniform branch)
  unsigned int vzr = 0, vc = 0;
  if (is_gate) { vzr = *mzr; vc = *mc; }
  mzr += mxstride; mc += mxstride;

  __syncthreads();

  for (int t = 0; t < T_STEPS; ++t) {
    // issue NEXT step's mx loads (gate waves); consumed one step later.
    // Final iteration reads one slot past MXzr/MXc (adjacent ws region, unused).
    unsigned int nzr = 0, nc = 0;
    if (is_gate) { nzr = *mzr; nc = *mc; }
    mzr += mxstride; mc += mxstride;

    const i32x4* hp = &hAv[t & 1][0];
    i32x4 af0 = hp[0 * 64 + lane];
    i32x4 af1 = hp[1 * 64 + lane];
    i32x4 af2 = hp[2 * 64 + lane];
    i32x4 af3 = hp[3 * 64 + lane];

    i32x4 az = {0, 0, 0, 0}, ar = {0, 0, 0, 0}, ac = {0, 0, 0, 0};
    az = __builtin_amdgcn_mfma_i32_16x16x64_i8(af0, bz[0], az, 0, 0, 0);
    ar = __builtin_amdgcn_mfma_i32_16x16x64_i8(af0, br[0], ar, 0, 0, 0);
    ac = __builtin_amdgcn_mfma_i32_16x16x64_i8(af0, bc[0], ac, 0, 0, 0);
    az = __builtin_amdgcn_mfma_i32_16x16x64_i8(af1, bz[1], az, 0, 0, 0);
    ar = __builtin_amdgcn_mfma_i32_16x16x64_i8(af1, br[1], ar, 0, 0, 0);
    ac = __builtin_amdgcn_mfma_i32_16x16x64_i8(af1, bc[1], ac, 0, 0, 0);
    az = __builtin_amdgcn_mfma_i32_16x16x64_i8(af2, bz[2], az, 0, 0, 0);
    ar = __builtin_amdgcn_mfma_i32_16x16x64_i8(af2, br[2], ar, 0, 0, 0);
    ac = __builtin_amdgcn_mfma_i32_16x16x64_i8(af2, bc[2], ac, 0, 0, 0);
    az = __builtin_amdgcn_mfma_i32_16x16x64_i8(af3, bz[3], az, 0, 0, 0);
    ar = __builtin_amdgcn_mfma_i32_16x16x64_i8(af3, br[3], ar, 0, 0, 0);
    ac = __builtin_amdgcn_mfma_i32_16x16x64_i8(af3, bc[3], ac, 0, 0, 0);

    // dump row-0 accumulators (full z/r/c for 16 units) to zrc
    if (lane < 16) {
      zrc[w * 48 + lane]      = az[0];
      zrc[w * 48 + 16 + lane] = ar[0];
      zrc[w * 48 + 32 + lane] = ac[0];
    }
    __syncthreads();   // barrier A: zrc visible; hAv[t&1] reads complete

    if (is_gate) {
      float zi = (float)zrc[zaddr];
      float ri = (float)zrc[zaddr + 16];
      float ci = (float)zrc[zaddr + 32];
      float xz = __uint_as_float(vzr << 16);
      float xr = __uint_as_float(vzr & 0xffff0000u);
      float xc = __uint_as_float(((unsigned int)vc) << 16);
      float tz = 1.0f + EXP2(fminf(__fmaf_rn(zi, szp, xz), 30.0f));
      float tr = 1.0f + EXP2(fminf(__fmaf_rn(ri, srp, xr), 30.0f));
      float R  = __builtin_amdgcn_rcpf(tz * tr);
      float zg = tr * R;                        // sigmoid(z)
      float rg = tz * R;                        // sigmoid(r)
      float mcv = __fmaf_rn(ci, scp, brcp);
      float tc = 1.0f + EXP2(__fmaf_rn(rg, mcv, xc)); // inf -> cand=-1 (exact limit)
      float cand = __fmaf_rn(2.0f, __builtin_amdgcn_rcpf(tc), -1.0f);  // tanh
      h = __fmaf_rn(zg, h - cand, cand);
      float q = __fmaf_rn(h, 127.0f, MAGIC);
      ((signed char*)hAv)[(((t & 1) ^ 1) * 4096) + hwb] = (signed char)(__float_as_uint(q) & 0xFF);
    }
    vzr = nzr;
    vc  = nc;
    __syncthreads();   // barrier B: hAv[(t+1)&1] ready for next step's MFMAs
  }

  // epilogue: logits = h @ w_out + b_out -> sigmoid
  if (is_gate) hout[u] = h;
  __syncthreads();
  if (tid < 64) {
    float p = 0.0f;
#pragma unroll
    for (int k = 0; k < 4; ++k) p += hout[tid + 64 * k] * w_out[tid + 64 * k];
    p += __shfl_down(p, 32, 64);
    p += __shfl_down(p, 16, 64);
    p += __shfl_down(p, 8, 64);
    p += __shfl_down(p, 4, 64);
    p += __shfl_down(p, 2, 64);
    p += __shfl_down(p, 1, 64);
    if (tid == 0) out[g] = sigmoidf_(p + b_out[0]);
  }
}

extern "C" void kernel_launch(void* const* d_in, const int* in_sizes, int n_in,
                              void* d_out, int out_size, void* d_ws, size_t ws_size,
                              hipStream_t stream) {
  const int*   inputs = (const int*)d_in[0];
  const float* emb    = (const float*)d_in[1];
  const float* kern   = (const float*)d_in[2];
  const float* rkern  = (const float*)d_in[3];
  const float* bias_i = (const float*)d_in[4];
  const float* bias_r = (const float*)d_in[5];
  const float* w_out  = (const float*)d_in[6];
  const float* b_out  = (const float*)d_in[7];
  float* out = (float*)d_out;

  char* ws = (char*)d_ws;
  size_t off = 0;
  size_t mxn = (size_t)T_STEPS * BATCH * 256;                          // 6.55M entries
  unsigned int*   MXzr = (unsigned int*)(ws + off);   off += mxn * 4;  // 26.2 MB
  unsigned short* MXc  = (unsigned short*)(ws + off); off += mxn * 2;  // 13.1 MB
  signed char*    w8   = (signed char*)(ws + off);    off += (size_t)W8_BYTES;     // 192 KB
  unsigned short* wfx  = (unsigned short*)(ws + off); off += (size_t)WFX_ELEMS * 2;// 192 KB
  float* cm   = (float*)(ws + off); off += (size_t)N3 * 4;
  float* bsum = (float*)(ws + off); off += (size_t)N3 * 4;
  if (off > ws_size) return;  // insufficient scratch -> visible failure, no corruption

  int prep_blocks = 48 + (WFX_ELEMS + N3 + 255) / 256;
  prep_kernel<<<dim3(prep_blocks), dim3(256), 0, stream>>>(
      kern, rkern, bias_i, bias_r, w8, wfx, bsum, cm);
  mx_kernel<<<dim3(1600), dim3(256), 0, stream>>>(inputs, emb, wfx, bsum, MXzr, MXc);
  gru_kernel<<<dim3(NG), dim3(1024), 0, stream>>>(MXzr, MXc, w8, cm, bias_r, w_out, b_out, out);
}

// Round 14
// 147.926 us; speedup vs baseline: 1.1438x; 1.1438x over previous
//
#include <hip/hip_runtime.h>
#include <stdint.h>

typedef __attribute__((ext_vector_type(8))) short short8;
typedef __attribute__((ext_vector_type(4))) short short4v;
typedef __attribute__((ext_vector_type(4))) float f32x4;
typedef __attribute__((ext_vector_type(4))) int   i32x4;

#define T_STEPS 200
#define BATCH   128
#define UNITS   256
#define N3      768
#define EMB_D   100

#define NG 128      // one block per batch row
#define GWAVES 16   // waves per gru block

#define W8_BYTES  (48 * 4 * 64 * 16)         // 196608 == 256*768 i8 frags
#define WFX_ELEMS (48 * 4 * 64 * 8)          // 98304  == 128*768 bf16 (K padded 100->128)

#define NLOG2E  -1.4426950408889634f         // -log2(e), folded into z/r columns
#define N2LOG2E -2.8853900817779268f         // -2*log2(e), folded into c columns

#if __has_builtin(__builtin_amdgcn_exp2f)
#define EXP2(x) __builtin_amdgcn_exp2f(x)
#else
#define EXP2(x) __expf((x) * 0.6931471805599453f)
#endif

__device__ __forceinline__ unsigned short f2bf(float f) {
  unsigned int u = __float_as_uint(f);
  u = (u + 0x7fffu + ((u >> 16) & 1u)) >> 16;   // RNE
  return (unsigned short)u;
}
__device__ __forceinline__ float sigmoidf_(float x) {
  return __builtin_amdgcn_rcpf(1.0f + __expf(-x));
}

// ------- kernel 0: fused per-column absmax + i8 quant; kernel->bf16 frags; bsum ------
__global__ void prep_kernel(const float* __restrict__ kern,
                            const float* __restrict__ rkern,
                            const float* __restrict__ bias_i,
                            const float* __restrict__ bias_r,
                            signed char* __restrict__ w8,
                            unsigned short* __restrict__ wfx,
                            float* __restrict__ bsum,
                            float* __restrict__ cm) {
  int b = blockIdx.x;
  int tid = threadIdx.x;
  if (b < 48) {
    __shared__ float red[256];
    __shared__ float cmv[16];
    int ntg = b;
    int col = tid & 15;
    int n = ntg * 16 + col;
    int k0 = (tid >> 4) * 16;
    float m = 0.0f;
#pragma unroll 4
    for (int k = k0; k < k0 + 16; ++k) m = fmaxf(m, fabsf(rkern[k * N3 + n]));
    red[tid] = m;
    __syncthreads();
    if (tid < 16) {
      float mm = red[tid];
#pragma unroll
      for (int s = 1; s < 16; ++s) mm = fmaxf(mm, red[tid + 16 * s]);
      mm = (mm > 0.0f) ? mm : 1.0f;
      cmv[tid] = mm;
      cm[n] = mm;                           // n == ntg*16 + tid here
    }
    __syncthreads();
    // quantize: thread tid -> bytes [ntg*4096 + tid*16, +16)
    int l = tid & 63, kc = tid >> 6;
    int nn = ntg * 16 + (l & 15);
    float inv127 = 127.0f / cmv[l & 15];
    union { signed char c[16]; i32x4 v; } pk;
#pragma unroll
    for (int e = 0; e < 16; ++e) {
      int k = kc * 64 + (e & 3) + ((l >> 4) & 3) * 4 + ((e >> 2) & 3) * 16;
      float v = rintf(rkern[k * N3 + nn] * inv127);
      v = fminf(127.0f, fmaxf(-127.0f, v));
      pk.c[e] = (signed char)(int)v;
    }
    *(i32x4*)&w8[ntg * 4096 + tid * 16] = pk.v;
  } else {
    int i = (b - 48) * 256 + tid;
    if (i < WFX_ELEMS) {
      int e = i & 7, l = (i >> 3) & 63, ks = (i >> 9) & 3, nt = i >> 11;
      int k = ks * 32 + (e >> 2) * 16 + ((l >> 4) & 3) * 4 + (e & 3);
      int n = nt * 16 + (l & 15);
      float gf = (n < 2 * UNITS) ? NLOG2E : N2LOG2E; // fold exp2 scale into columns
      wfx[i] = (k < EMB_D) ? f2bf(kern[k * N3 + n] * gf) : (unsigned short)0;
    } else if (i < WFX_ELEMS + N3) {
      int c = i - WFX_ELEMS;
      float gf = (c < 2 * UNITS) ? NLOG2E : N2LOG2E;
      bsum[c] = (bias_i[c] + ((c < 2 * UNITS) ? bias_r[c] : 0.0f)) * gf;
    }
  }
}

// -------- kernel 1: MX = emb[inputs] @ kernel' + bsum', row-major packed -------------
// MXzr[m*256+u] = z|(r<<16) bf16 pair; MXc[m*256+u] = c bf16, m = t*128 + b.
__global__ __launch_bounds__(256) void mx_kernel(
    const int* __restrict__ inputs, const float* __restrict__ emb,
    const unsigned short* __restrict__ wfx, const float* __restrict__ bsum,
    unsigned int* __restrict__ MXzr, unsigned short* __restrict__ MXc) {
  __shared__ unsigned short Af[4 * 64 * 8];   // 4 KB A-fragments (16 rows x K128)
  __shared__ unsigned short stg[3 * 16 * 256];// 24 KB staging [gate][row16][u]
  int tile = blockIdx.x;                      // 1600 tiles of 16 m-rows
  int tid = threadIdx.x;
  int lane = tid & 63;
  int wv = tid >> 6;
  {
    short8 z = {0, 0, 0, 0, 0, 0, 0, 0};
    ((short8*)Af)[tid] = z;
  }
  __syncthreads();
  // vectorized gather: 16 rows x 25 float4 chunks (emb rows 16B-aligned at c%4==0)
  for (int i = tid; i < 512; i += 256) {
    int r = i >> 5, c4 = i & 31;
    if (c4 < 25) {
      int m = tile * 16 + r;                  // m = t*128 + b
      int ti = m >> 7, b = m & 127;
      int word = inputs[b * T_STEPS + ti];
      f32x4 v = *(const f32x4*)(emb + word * EMB_D + c4 * 4);
      int c = c4 * 4;
      int idx0 = ((c >> 5) * 64 + (r + 16 * ((c >> 2) & 3))) * 8 + ((c >> 4) & 1) * 4;
      short4v p = {(short)f2bf(v.x), (short)f2bf(v.y), (short)f2bf(v.z), (short)f2bf(v.w)};
      *(short4v*)&Af[idx0] = p;               // (c&3)=0..3 are contiguous in frag order
    }
  }
  __syncthreads();
  short8 a0 = ((short8*)Af)[0 * 64 + lane];
  short8 a1 = ((short8*)Af)[1 * 64 + lane];
  short8 a2 = ((short8*)Af)[2 * 64 + lane];
  short8 a3 = ((short8*)Af)[3 * 64 + lane];
  int r0 = (lane >> 4) * 4;
  for (int q = 0; q < 12; ++q) {
    int nt = wv * 12 + q;
    f32x4 acc = {0.f, 0.f, 0.f, 0.f};
    const short8* bp = (const short8*)(wfx) + (nt * 4) * 64 + lane;
    acc = __builtin_amdgcn_mfma_f32_16x16x32_bf16(a0, bp[0],   acc, 0, 0, 0);
    acc = __builtin_amdgcn_mfma_f32_16x16x32_bf16(a1, bp[64],  acc, 0, 0, 0);
    acc = __builtin_amdgcn_mfma_f32_16x16x32_bf16(a2, bp[128], acc, 0, 0, 0);
    acc = __builtin_amdgcn_mfma_f32_16x16x32_bf16(a3, bp[192], acc, 0, 0, 0);
    int col = nt * 16 + (lane & 15);
    float bs = bsum[col];
    int gate = col >> 8, u = col & 255;
    int base = gate * 4096 + r0 * 256 + u;
#pragma unroll
    for (int j = 0; j < 4; ++j) stg[base + j * 256] = f2bf(acc[j] + bs);
  }
  __syncthreads();
  // repack: row-major (m, u), coalesced over u
  for (int i = tid; i < 4096; i += 256) {
    int r = i >> 8, u = i & 255;
    size_t m = (size_t)tile * 16 + r;
    unsigned int z = stg[r * 256 + u];
    unsigned int rr = stg[4096 + r * 256 + u];
    unsigned int c = stg[8192 + r * 256 + u];
    MXzr[m * 256 + u] = z | (rr << 16);
    MXc[m * 256 + u] = (unsigned short)c;
  }
}

// -------- kernel 2: RR=1 — gates straight off accumulators, no LDS exchange ----------
__global__ __launch_bounds__(1024) void gru_kernel(
    const unsigned int* __restrict__ MXzr, const unsigned short* __restrict__ MXc,
    const signed char* __restrict__ w8,
    const float* __restrict__ cm, const float* __restrict__ bias_r,
    const float* __restrict__ w_out, const float* __restrict__ b_out,
    float* __restrict__ out) {
  __shared__ i32x4 hAv[2][4 * 64];            // 8 KB: double-buffered h i8 A-frags (row 0 only)
  __shared__ float hout[UNITS];               // 1 KB: final h for output GEMV

  int g = blockIdx.x;                          // batch row 0..127
  int tid = threadIdx.x;
  int lane = tid & 63;
  int wv = tid >> 6;                           // 0..15

  // persistent weights: wave wv owns gate-aligned ntile triple {wv, 16+wv, 32+wv}
  i32x4 bz[4], br[4], bc[4];
  {
    const i32x4* wsrc = (const i32x4*)w8 + lane;
#pragma unroll
    for (int kc = 0; kc < 4; ++kc) {
      bz[kc] = wsrc[(size_t)((wv)*4 + kc) * 64];
      br[kc] = wsrc[(size_t)((16 + wv) * 4 + kc) * 64];
      bc[kc] = wsrc[(size_t)((32 + wv) * 4 + kc) * 64];
    }
  }
  if (tid < 512) { i32x4 z = {0, 0, 0, 0}; ((i32x4*)hAv)[tid] = z; }

  int l15 = lane & 15;
  int u = wv * 16 + l15;                       // this thread's gate unit (lanes 0-15 live)
  const float inv = 1.0f / (127.0f * 127.0f);
  float szp = cm[u] * inv * NLOG2E;
  float srp = cm[u + UNITS] * inv * NLOG2E;
  float scp = cm[u + 2 * UNITS] * inv * N2LOG2E;
  float brcp = bias_r[2 * UNITS + u] * N2LOG2E;

  // hA byte-write base for (row0, u): plane kc=u>>6 (1024 B), lane la=16*((u>>2)&3),
  // byte e=(u&3)+4*((u>>4)&3). Buffer stride 4096 B. Bijective over u (bits 7..0).
  int hwb = (u >> 6) * 1024 + (16 * ((u >> 2) & 3)) * 16 + (u & 3) + 4 * ((u >> 4) & 3);

  float h = 0.0f;
  const unsigned int* mzr = MXzr + (size_t)g * 256 + u;
  const unsigned short* mc = MXc + (size_t)g * 256 + u;
  const size_t mxstride = (size_t)BATCH * 256;
  const float MAGIC = 12582912.0f;             // 2^23 + 2^22

  // prefetch t=0 (lanes>=16 fetch duplicates of the same cache line; harmless)
  unsigned int vzr = *mzr;  mzr += mxstride;
  unsigned int vc  = *mc;   mc  += mxstride;

  const i32x4 ZERO = {0, 0, 0, 0};             // shared C-operand, live across the loop

  __syncthreads();

  for (int t = 0; t < T_STEPS; ++t) {
    // issue NEXT step's mx loads; consumed one full step later -> latency hidden.
    // Final iteration reads one slot past MXzr/MXc (adjacent ws region, unused).
    unsigned int nzr = *mzr;  mzr += mxstride;
    unsigned int nc  = *mc;   mc  += mxstride;

    const i32x4* hp = &hAv[t & 1][0];
    i32x4 af0 = hp[0 * 64 + lane];
    i32x4 af1 = hp[1 * 64 + lane];
    i32x4 af2 = hp[2 * 64 + lane];
    i32x4 af3 = hp[3 * 64 + lane];

    i32x4 az = __builtin_amdgcn_mfma_i32_16x16x64_i8(af0, bz[0], ZERO, 0, 0, 0);
    i32x4 ar = __builtin_amdgcn_mfma_i32_16x16x64_i8(af0, br[0], ZERO, 0, 0, 0);
    i32x4 ac = __builtin_amdgcn_mfma_i32_16x16x64_i8(af0, bc[0], ZERO, 0, 0, 0);
    az = __builtin_amdgcn_mfma_i32_16x16x64_i8(af1, bz[1], az, 0, 0, 0);
    ar = __builtin_amdgcn_mfma_i32_16x16x64_i8(af1, br[1], ar, 0, 0, 0);
    ac = __builtin_amdgcn_mfma_i32_16x16x64_i8(af1, bc[1], ac, 0, 0, 0);
    az = __builtin_amdgcn_mfma_i32_16x16x64_i8(af2, bz[2], az, 0, 0, 0);
    ar = __builtin_amdgcn_mfma_i32_16x16x64_i8(af2, br[2], ar, 0, 0, 0);
    ac = __builtin_amdgcn_mfma_i32_16x16x64_i8(af2, bc[2], ac, 0, 0, 0);
    az = __builtin_amdgcn_mfma_i32_16x16x64_i8(af3, bz[3], az, 0, 0, 0);
    ar = __builtin_amdgcn_mfma_i32_16x16x64_i8(af3, br[3], ar, 0, 0, 0);
    ac = __builtin_amdgcn_mfma_i32_16x16x64_i8(af3, bc[3], ac, 0, 0, 0);

    // gate phase: lanes 0-15 hold the full (z,r,c) triple for unit u in
    // az[0]/ar[0]/ac[0] (row 0 of the D fragment) — no exchange needed.
    float zi = (float)az[0];
    float ri = (float)ar[0];
    float ci = (float)ac[0];
    float xz = __uint_as_float(vzr << 16);
    float xr = __uint_as_float(vzr & 0xffff0000u);
    float xc = __uint_as_float(((unsigned int)vc) << 16);
    float tz = 1.0f + EXP2(fminf(__fmaf_rn(zi, szp, xz), 30.0f));
    float tr = 1.0f + EXP2(fminf(__fmaf_rn(ri, srp, xr), 30.0f));
    float R  = __builtin_amdgcn_rcpf(tz * tr);
    float zg = tr * R;                          // sigmoid(z)
    float rg = tz * R;                          // sigmoid(r)
    float mcv = __fmaf_rn(ci, scp, brcp);
    float tc = 1.0f + EXP2(__fmaf_rn(rg, mcv, xc));  // inf -> rcp=0 -> cand=-1 (exact limit)
    float cand = __fmaf_rn(2.0f, __builtin_amdgcn_rcpf(tc), -1.0f);  // tanh
    h = __fmaf_rn(zg, h - cand, cand);
    if (lane < 16) {
      float q = __fmaf_rn(h, 127.0f, MAGIC);
      ((signed char*)hAv)[(((t & 1) ^ 1) * 4096) + hwb] = (signed char)(__float_as_uint(q) & 0xFF);
    }
    vzr = nzr;
    vc  = nc;
    // single barrier/step: step t reads hAv[t&1] BEFORE it; step t+1 writes
    // hAv[t&1] AFTER it -> ping-pong is hazard-free with one barrier.
    __syncthreads();
  }

  // epilogue: logits = h @ w_out + b_out -> sigmoid
  if (lane < 16) hout[u] = h;
  __syncthreads();
  if (tid < 64) {
    float p = 0.0f;
#pragma unroll
    for (int k = 0; k < 4; ++k) p += hout[tid + 64 * k] * w_out[tid + 64 * k];
    p += __shfl_down(p, 32, 64);
    p += __shfl_down(p, 16, 64);
    p += __shfl_down(p, 8, 64);
    p += __shfl_down(p, 4, 64);
    p += __shfl_down(p, 2, 64);
    p += __shfl_down(p, 1, 64);
    if (tid == 0) out[g] = sigmoidf_(p + b_out[0]);
  }
}

extern "C" void kernel_launch(void* const* d_in, const int* in_sizes, int n_in,
                              void* d_out, int out_size, void* d_ws, size_t ws_size,
                              hipStream_t stream) {
  const int*   inputs = (const int*)d_in[0];
  const float* emb    = (const float*)d_in[1];
  const float* kern   = (const float*)d_in[2];
  const float* rkern  = (const float*)d_in[3];
  const float* bias_i = (const float*)d_in[4];
  const float* bias_r = (const float*)d_in[5];
  const float* w_out  = (const float*)d_in[6];
  const float* b_out  = (const float*)d_in[7];
  float* out = (float*)d_out;

  char* ws = (char*)d_ws;
  size_t off = 0;
  size_t mxn = (size_t)T_STEPS * BATCH * 256;                          // 6.55M entries
  unsigned int*   MXzr = (unsigned int*)(ws + off);   off += mxn * 4;  // 26.2 MB
  unsigned short* MXc  = (unsigned short*)(ws + off); off += mxn * 2;  // 13.1 MB
  signed char*    w8   = (signed char*)(ws + off);    off += (size_t)W8_BYTES;     // 192 KB
  unsigned short* wfx  = (unsigned short*)(ws + off); off += (size_t)WFX_ELEMS * 2;// 192 KB
  float* cm   = (float*)(ws + off); off += (size_t)N3 * 4;
  float* bsum = (float*)(ws + off); off += (size_t)N3 * 4;
  if (off > ws_size) return;  // insufficient scratch -> visible failure, no corruption

  int prep_blocks = 48 + (WFX_ELEMS + N3 + 255) / 256;
  prep_kernel<<<dim3(prep_blocks), dim3(256), 0, stream>>>(
      kern, rkern, bias_i, bias_r, w8, wfx, bsum, cm);
  mx_kernel<<<dim3(1600), dim3(256), 0, stream>>>(inputs, emb, wfx, bsum, MXzr, MXc);
  gru_kernel<<<dim3(NG), dim3(1024), 0, stream>>>(MXzr, MXc, w8, cm, bias_r, w_out, b_out, out);
}